// Round 1
// baseline (253.494 us; speedup 1.0000x reference)
//
#include <hip/hip_runtime.h>

#define L_MAX 16
#define MARGIN 0.4f
#define EPS 1e-8f

// One 64-lane wave per pair. Lane l owns D-elements [l*4 + k*256 .. +3] for
// k=0..3 (float4-strided so each of the 4 loads per row is one fully
// coalesced 1 KiB wave transaction).
__global__ __launch_bounds__(256) void span_pair_loss_kernel(
    const float* __restrict__ emb,
    const int*   __restrict__ sid,
    const int*   __restrict__ s_start,
    const int*   __restrict__ s_len,
    const int*   __restrict__ t_start,
    const int*   __restrict__ t_len,
    const int*   __restrict__ labels,
    float*       __restrict__ loss_out,
    int N, int S, int D)
{
    const int wid  = (int)((blockIdx.x * blockDim.x + threadIdx.x) >> 6);
    const int lane = (int)(threadIdx.x & 63);
    if (wid >= N) return;

    const int b = sid[wid];
    const float* __restrict__ base = emb + (size_t)b * (size_t)S * (size_t)D;

    float4 smax[4], tmax[4];

    // ---- s span max-pool (wave-uniform length -> no divergence) ----
    {
        const int st = s_start[wid];
        const int ln = s_len[wid];              // extra rows beyond the first
        const float4* __restrict__ row = reinterpret_cast<const float4*>(base + (size_t)st * D);
        const int D4 = D >> 2;                  // 256 float4s per row
        #pragma unroll
        for (int k = 0; k < 4; ++k)
            smax[k] = row[k * 64 + lane];
        for (int j = 1; j <= ln; ++j) {
            const float4* __restrict__ r = row + (size_t)j * D4;
            #pragma unroll
            for (int k = 0; k < 4; ++k) {
                float4 v = r[k * 64 + lane];
                smax[k].x = fmaxf(smax[k].x, v.x);
                smax[k].y = fmaxf(smax[k].y, v.y);
                smax[k].z = fmaxf(smax[k].z, v.z);
                smax[k].w = fmaxf(smax[k].w, v.w);
            }
        }
    }

    // ---- t span max-pool ----
    {
        const int st = t_start[wid];
        const int ln = t_len[wid];
        const float4* __restrict__ row = reinterpret_cast<const float4*>(base + (size_t)st * D);
        const int D4 = D >> 2;
        #pragma unroll
        for (int k = 0; k < 4; ++k)
            tmax[k] = row[k * 64 + lane];
        for (int j = 1; j <= ln; ++j) {
            const float4* __restrict__ r = row + (size_t)j * D4;
            #pragma unroll
            for (int k = 0; k < 4; ++k) {
                float4 v = r[k * 64 + lane];
                tmax[k].x = fmaxf(tmax[k].x, v.x);
                tmax[k].y = fmaxf(tmax[k].y, v.y);
                tmax[k].z = fmaxf(tmax[k].z, v.z);
                tmax[k].w = fmaxf(tmax[k].w, v.w);
            }
        }
    }

    // ---- per-lane partials ----
    float dot = 0.f, ss = 0.f, tt = 0.f;
    #pragma unroll
    for (int k = 0; k < 4; ++k) {
        dot += smax[k].x * tmax[k].x + smax[k].y * tmax[k].y
             + smax[k].z * tmax[k].z + smax[k].w * tmax[k].w;
        ss  += smax[k].x * smax[k].x + smax[k].y * smax[k].y
             + smax[k].z * smax[k].z + smax[k].w * smax[k].w;
        tt  += tmax[k].x * tmax[k].x + tmax[k].y * tmax[k].y
             + tmax[k].z * tmax[k].z + tmax[k].w * tmax[k].w;
    }

    // ---- 64-lane shuffle reduction ----
    #pragma unroll
    for (int off = 32; off > 0; off >>= 1) {
        dot += __shfl_down(dot, off, 64);
        ss  += __shfl_down(ss,  off, 64);
        tt  += __shfl_down(tt,  off, 64);
    }

    if (lane == 0) {
        float cosv = dot / (sqrtf(ss) * sqrtf(tt) + EPS);
        float l = (labels[wid] > 0) ? (1.0f - cosv)
                                    : fmaxf(0.0f, cosv - MARGIN);
        loss_out[wid] = l;
    }
}

// Single-block deterministic mean over N per-pair losses.
__global__ __launch_bounds__(256) void mean_reduce_kernel(
    const float* __restrict__ loss, float* __restrict__ out, int N)
{
    float sum = 0.f;
    for (int i = (int)threadIdx.x; i < N; i += 256)
        sum += loss[i];
    #pragma unroll
    for (int off = 32; off > 0; off >>= 1)
        sum += __shfl_down(sum, off, 64);

    __shared__ float sdata[4];
    const int w = (int)(threadIdx.x >> 6);
    if ((threadIdx.x & 63) == 0) sdata[w] = sum;
    __syncthreads();
    if (threadIdx.x == 0)
        out[0] = (sdata[0] + sdata[1] + sdata[2] + sdata[3]) / (float)N;
}

extern "C" void kernel_launch(void* const* d_in, const int* in_sizes, int n_in,
                              void* d_out, int out_size, void* d_ws, size_t ws_size,
                              hipStream_t stream) {
    const float* emb     = (const float*)d_in[0];
    const int*   sid     = (const int*)d_in[1];
    const int*   s_start = (const int*)d_in[2];
    const int*   s_len   = (const int*)d_in[3];
    const int*   t_start = (const int*)d_in[4];
    const int*   t_len   = (const int*)d_in[5];
    const int*   labels  = (const int*)d_in[6];

    const int N = in_sizes[1];          // 8192 pairs
    const int S = 512;
    const int D = 1024;                 // per reference setup_inputs()

    float* loss_ws = (float*)d_ws;      // N floats of scratch

    const int waves_per_block = 4;      // 256 threads
    const int blocks = (N + waves_per_block - 1) / waves_per_block;

    span_pair_loss_kernel<<<blocks, 256, 0, stream>>>(
        emb, sid, s_start, s_len, t_start, t_len, labels, loss_ws, N, S, D);

    mean_reduce_kernel<<<1, 256, 0, stream>>>(loss_ws, (float*)d_out, N);
}

// Round 2
// 251.573 us; speedup vs baseline: 1.0076x; 1.0076x over previous
//
#include <hip/hip_runtime.h>

#define L_MAX 16
#define MARGIN 0.4f
#define EPS 1e-8f
#define NSENT 64

// ---------- pass 1: per-sentence histogram + exclusive scan (1 block) ----------
__global__ __launch_bounds__(256) void hist_scan_kernel(
    const int* __restrict__ sid, int* __restrict__ cursor, int N)
{
    __shared__ int h[NSENT];
    const int t = (int)threadIdx.x;
    if (t < NSENT) h[t] = 0;
    __syncthreads();
    for (int i = t; i < N; i += 256)
        atomicAdd(&h[sid[i]], 1);
    __syncthreads();
    if (t == 0) {
        int acc = 0;
        for (int b = 0; b < NSENT; ++b) { int c = h[b]; cursor[b] = acc; acc += c; }
    }
}

// ---------- pass 2: scatter pair ids into sid-sorted order ----------
__global__ __launch_bounds__(256) void scatter_kernel(
    const int* __restrict__ sid, int* __restrict__ cursor,
    int* __restrict__ perm, int N)
{
    const int i = (int)(blockIdx.x * 256 + threadIdx.x);
    if (i < N) {
        const int p = atomicAdd(&cursor[sid[i]], 1);
        perm[p] = i;   // nondeterministic within a sentence; output-indexed write below keeps result deterministic
    }
}

// ---------- pass 3: one wave per pair, sid-grouped + XCD-swizzled ----------
// Lane l owns float4 chunks {k*64+l : k=0..3} of D=1024 -> 4 coalesced 1KiB
// wave transactions per row. s/t loops fused for 2x memory-level parallelism.
__global__ __launch_bounds__(256) void span_pair_loss_kernel(
    const float* __restrict__ emb,
    const int*   __restrict__ sid,
    const int*   __restrict__ s_start,
    const int*   __restrict__ s_len,
    const int*   __restrict__ t_start,
    const int*   __restrict__ t_len,
    const int*   __restrict__ labels,
    const int*   __restrict__ perm,
    float*       __restrict__ loss_out,
    int N, int S, int D)
{
    // bijective XCD swizzle (m204): block `orig` runs on XCD orig%8 (round-robin
    // heuristic); remap so each XCD walks a CONTIGUOUS chunk of the sid-sorted
    // pair list -> working set ~2 sentences = 4 MiB = one XCD L2.
    const int orig = (int)blockIdx.x;
    const int nwg  = (int)gridDim.x;
    const int q = nwg >> 3, r = nwg & 7;
    const int x = orig & 7, j = orig >> 3;
    const int swz = (x < r ? x * (q + 1) : r * (q + 1) + (x - r) * q) + j;

    const int lane  = (int)(threadIdx.x & 63);
    const int pslot = swz * 4 + (int)(threadIdx.x >> 6);
    if (pslot >= N) return;
    const int pid = perm[pslot];

    const int b  = sid[pid];
    const int ss = s_start[pid];
    const int ls = s_len[pid];
    const int ts = t_start[pid];
    const int lt = t_len[pid];

    const float* __restrict__ base = emb + (size_t)b * (size_t)S * (size_t)D;
    const int D4 = D >> 2;
    const float4* __restrict__ srow = reinterpret_cast<const float4*>(base + (size_t)ss * D);
    const float4* __restrict__ trow = reinterpret_cast<const float4*>(base + (size_t)ts * D);

    float4 sm[4], tm[4];
    #pragma unroll
    for (int k = 0; k < 4; ++k) sm[k] = srow[k * 64 + lane];
    #pragma unroll
    for (int k = 0; k < 4; ++k) tm[k] = trow[k * 64 + lane];

    const int lmax = max(ls, lt);
    for (int jj = 1; jj <= lmax; ++jj) {      // wave-uniform trip count
        float4 a[4], c[4];
        const bool ds = (jj <= ls), dt = (jj <= lt);
        if (ds) {
            #pragma unroll
            for (int k = 0; k < 4; ++k) a[k] = srow[(size_t)jj * D4 + k * 64 + lane];
        }
        if (dt) {
            #pragma unroll
            for (int k = 0; k < 4; ++k) c[k] = trow[(size_t)jj * D4 + k * 64 + lane];
        }
        if (ds) {
            #pragma unroll
            for (int k = 0; k < 4; ++k) {
                sm[k].x = fmaxf(sm[k].x, a[k].x); sm[k].y = fmaxf(sm[k].y, a[k].y);
                sm[k].z = fmaxf(sm[k].z, a[k].z); sm[k].w = fmaxf(sm[k].w, a[k].w);
            }
        }
        if (dt) {
            #pragma unroll
            for (int k = 0; k < 4; ++k) {
                tm[k].x = fmaxf(tm[k].x, c[k].x); tm[k].y = fmaxf(tm[k].y, c[k].y);
                tm[k].z = fmaxf(tm[k].z, c[k].z); tm[k].w = fmaxf(tm[k].w, c[k].w);
            }
        }
    }

    float dot = 0.f, ssq = 0.f, tsq = 0.f;
    #pragma unroll
    for (int k = 0; k < 4; ++k) {
        dot += sm[k].x * tm[k].x + sm[k].y * tm[k].y + sm[k].z * tm[k].z + sm[k].w * tm[k].w;
        ssq += sm[k].x * sm[k].x + sm[k].y * sm[k].y + sm[k].z * sm[k].z + sm[k].w * sm[k].w;
        tsq += tm[k].x * tm[k].x + tm[k].y * tm[k].y + tm[k].z * tm[k].z + tm[k].w * tm[k].w;
    }

    #pragma unroll
    for (int off = 32; off > 0; off >>= 1) {
        dot += __shfl_down(dot, off, 64);
        ssq += __shfl_down(ssq, off, 64);
        tsq += __shfl_down(tsq, off, 64);
    }

    if (lane == 0) {
        const float cosv = dot / (sqrtf(ssq) * sqrtf(tsq) + EPS);
        const float l = (labels[pid] > 0) ? (1.0f - cosv)
                                          : fmaxf(0.0f, cosv - MARGIN);
        loss_out[pid] = l;   // indexed by ORIGINAL pair id -> deterministic mean
    }
}

// ---------- pass 4: deterministic mean ----------
__global__ __launch_bounds__(256) void mean_reduce_kernel(
    const float* __restrict__ loss, float* __restrict__ out, int N)
{
    float sum = 0.f;
    for (int i = (int)threadIdx.x; i < N; i += 256)
        sum += loss[i];
    #pragma unroll
    for (int off = 32; off > 0; off >>= 1)
        sum += __shfl_down(sum, off, 64);

    __shared__ float sdata[4];
    const int w = (int)(threadIdx.x >> 6);
    if ((threadIdx.x & 63) == 0) sdata[w] = sum;
    __syncthreads();
    if (threadIdx.x == 0)
        out[0] = (sdata[0] + sdata[1] + sdata[2] + sdata[3]) / (float)N;
}

extern "C" void kernel_launch(void* const* d_in, const int* in_sizes, int n_in,
                              void* d_out, int out_size, void* d_ws, size_t ws_size,
                              hipStream_t stream) {
    const float* emb     = (const float*)d_in[0];
    const int*   sid     = (const int*)d_in[1];
    const int*   s_start = (const int*)d_in[2];
    const int*   s_len   = (const int*)d_in[3];
    const int*   t_start = (const int*)d_in[4];
    const int*   t_len   = (const int*)d_in[5];
    const int*   labels  = (const int*)d_in[6];

    const int N = in_sizes[1];          // 8192 pairs
    const int S = 512;
    const int D = 1024;

    // workspace layout: [N floats loss][N ints perm][64 ints cursor]
    float* loss_ws = (float*)d_ws;
    int*   perm    = (int*)((char*)d_ws + (size_t)N * 4);
    int*   cursor  = (int*)((char*)d_ws + (size_t)N * 8);

    hist_scan_kernel<<<1, 256, 0, stream>>>(sid, cursor, N);
    scatter_kernel<<<(N + 255) / 256, 256, 0, stream>>>(sid, cursor, perm, N);

    const int blocks = (N + 3) / 4;     // 4 waves (pairs) per 256-thread block
    span_pair_loss_kernel<<<blocks, 256, 0, stream>>>(
        emb, sid, s_start, s_len, t_start, t_len, labels, perm, loss_ws, N, S, D);

    mean_reduce_kernel<<<1, 256, 0, stream>>>(loss_ws, (float*)d_out, N);
}